// Round 1
// baseline (491.877 us; speedup 1.0000x reference)
//
#include <hip/hip_runtime.h>
#include <math.h>

// Problem constants
#define NN   16
#define CI   64
#define HH   224
#define WW   224
#define CO   128
#define OHH  222
#define OWW  222

// Workspace layout:
//  [0, 147456)                : weight fragments, B-operand pre-swizzled per-lane order
//  [147456, 147456+XTS_BYTES) : x transposed to NHWC bf16, per-w chunk-rotated
//  tail pad 64 KiB            : absorbs DMA overfetch of up to ~58 KB
#define WFRAG_BYTES (36*4*64*16)                 // 147456
#define XTS_OFF     ((size_t)WFRAG_BYTES)
#define XTS_SLOTS   (NN*HH*WW)                   // 802816 (n,h,w) slots, 128 B each
#define XTS_BYTES   ((size_t)XTS_SLOTS*128)      // 102,760,448
#define WS_NEED     (XTS_OFF + XTS_BYTES + 65536)

typedef short  short8  __attribute__((ext_vector_type(8)));
typedef float  f32x16  __attribute__((ext_vector_type(16)));

__device__ static inline unsigned short f2bf(float f) {
  unsigned u = __float_as_uint(f);
  u = (u + 0x7fffu + ((u >> 16) & 1u)) >> 16;   // RNE
  return (unsigned short)u;
}

// ---------------------------------------------------------------------------
// prep_x: NCHW fp32 -> ws NHWC bf16, 128 B per (n,h,w) slot.
// Within a slot, 16B ci-chunk c is stored at position (c + w) & 7 so that the
// main kernel's ds_read_b128 A-fragment reads rotate across LDS banks.
// ---------------------------------------------------------------------------
__global__ __launch_bounds__(256) void prep_x_kernel(const float* __restrict__ x,
                                                     unsigned char* __restrict__ ws) {
  int slot = blockIdx.x * 256 + threadIdx.x;       // 0..802815
  int n  = slot / (HH*WW);
  int hw = slot - n * (HH*WW);
  int w  = hw % WW;
  const float* xp = x + (size_t)n * CI * HH * WW + hw;
  unsigned int pk[32];
#pragma unroll
  for (int i = 0; i < 32; ++i) {
    float a = xp[(size_t)(2*i    ) * (HH*WW)];
    float b = xp[(size_t)(2*i + 1) * (HH*WW)];
    pk[i] = (unsigned)f2bf(a) | ((unsigned)f2bf(b) << 16);
  }
  uint4* dst = (uint4*)(ws + XTS_OFF + (size_t)slot * 128);
#pragma unroll
  for (int c = 0; c < 8; ++c) {
    dst[(c + w) & 7] = make_uint4(pk[4*c], pk[4*c+1], pk[4*c+2], pk[4*c+3]);
  }
}

// ---------------------------------------------------------------------------
// prep_w: weights [Co][Ci][3][3] fp32 -> B fragments in exact mfma lane order.
// Fragment f = s*4 + ct, s = tap*4 + cic, tap = kh*3+kw.
// B[k][n]: n = lane&31 (co within tile), k = (lane>>5)*8 + j  (ci within cic).
// ---------------------------------------------------------------------------
__global__ __launch_bounds__(256) void prep_w_kernel(const float* __restrict__ wt,
                                                     unsigned char* __restrict__ ws) {
  int t    = blockIdx.x * 256 + threadIdx.x;       // 0..9215
  int lane = t & 63;
  int f    = t >> 6;                               // 0..143
  int s    = f >> 2;
  int ct   = f & 3;
  int tap  = s >> 2;
  int cic  = s & 3;
  int kh   = tap / 3, kw = tap % 3;
  int co   = ct * 32 + (lane & 31);
  int k0   = cic * 16 + (lane >> 5) * 8;
  unsigned int pk[4];
#pragma unroll
  for (int j = 0; j < 4; ++j) {
    int ci0 = k0 + 2*j;
    float a = wt[(size_t)co*576 + (ci0    )*9 + kh*3 + kw];
    float b = wt[(size_t)co*576 + (ci0 + 1)*9 + kh*3 + kw];
    pk[j] = (unsigned)f2bf(a) | ((unsigned)f2bf(b) << 16);
  }
  ((uint4*)ws)[t] = make_uint4(pk[0], pk[1], pk[2], pk[3]);
}

// ---------------------------------------------------------------------------
// main kernel: per block, M = 256 pixels (4 oh x 64 ow), N = all 128 co.
// A tile staged once via global_load_lds (width 16); K-loop barrier-free.
// Wave wv owns output row oh0+wv: 2 m-tiles (owl 0..31 / 32..63) x 4 co-tiles.
// Epilogue: min over co is wave-internal; tanh(tanh()) + coalesced store.
// ---------------------------------------------------------------------------
__device__ static inline void lds_dma16(void* lds, const void* g) {
  __builtin_amdgcn_global_load_lds(
      (__attribute__((address_space(1))) void*)g,
      (__attribute__((address_space(3))) void*)lds, 16, 0, 0);
}

__global__ __launch_bounds__(256, 2) void conv_min_kernel(
    const float* __restrict__ bias, const unsigned char* __restrict__ ws,
    float* __restrict__ out) {
  __shared__ __align__(16) unsigned char smem[6 * 72 * 128];  // 55296 B
  __shared__ float scratch[256];

  int bid  = blockIdx.x;
  int owt  = bid & 3;
  int rest = bid >> 2;
  int oht  = rest % 56;
  int n    = rest / 56;
  int ow0  = (owt < 3) ? owt * 64 : 158;   // last tile overlaps; identical values
  int oh0  = oht * 4;                      // last tile: rows 2,3 masked at store

  int tid   = threadIdx.x;
  int wv    = tid >> 6;
  int lane  = tid & 63;
  int mrow  = lane & 31;
  int khalf = lane >> 5;

  // ---- stage A tile: 6 rows x (72 w x 64 ci bf16) = 6 x 9216 B, DMA ----
  const unsigned char* xts = ws + XTS_OFF;
  size_t gbase = ((size_t)(n * 224 + oh0) * 224 + ow0) * 128;
  for (int i = wv; i < 54; i += 4) {
    int r   = i / 9;
    int sub = i - r * 9;
    const unsigned char* gp = xts + gbase + (size_t)r * (224 * 128) + sub * 1024 + lane * 16;
    lds_dma16(smem + r * 9216 + sub * 1024, gp);
  }

  // ---- acc init with bias (col = co = ct*32 + (lane&31)) ----
  f32x16 acc[2][4];
#pragma unroll
  for (int ct = 0; ct < 4; ++ct) {
    float b = bias[ct * 32 + mrow];
#pragma unroll
    for (int mtl = 0; mtl < 2; ++mtl)
#pragma unroll
      for (int r = 0; r < 16; ++r) acc[mtl][ct][r] = b;
  }

  __syncthreads();   // drains the DMA (vmcnt) + all waves staged

  // ---- K loop: 9 taps x 4 ci-chunks, no barriers ----
  const short8* wf = (const short8*)ws;
#pragma unroll
  for (int kh = 0; kh < 3; ++kh) {
#pragma unroll
    for (int kw = 0; kw < 3; ++kw) {
      int rowb = (wv + kh) * 72;
#pragma unroll
      for (int cic = 0; cic < 4; ++cic) {
        int s = (kh * 3 + kw) * 4 + cic;
        int c = cic * 2 + khalf;              // 16B ci-chunk index 0..7
        int col0 = mrow + kw;                 // m-tile 0: owl = mrow
        int col1 = mrow + 32 + kw;            // m-tile 1: owl = mrow+32
        short8 a0 = *(const short8*)(smem + (rowb + col0) * 128 + (((c + ow0 + col0) & 7) << 4));
        short8 a1 = *(const short8*)(smem + (rowb + col1) * 128 + (((c + ow0 + col1) & 7) << 4));
#pragma unroll
        for (int ct = 0; ct < 4; ++ct) {
          short8 bfr = wf[(s * 4 + ct) * 64 + lane];
          acc[0][ct] = __builtin_amdgcn_mfma_f32_32x32x16_bf16(a0, bfr, acc[0][ct], 0, 0, 0);
          acc[1][ct] = __builtin_amdgcn_mfma_f32_32x32x16_bf16(a1, bfr, acc[1][ct], 0, 0, 0);
        }
      }
    }
  }

  // ---- epilogue: min over 128 co ----
  // C/D layout (measured m74/m101): col = lane&31 (co), row = (reg&3)+8*(reg>>2)+4*(lane>>5)
  float vmn[2][16];
#pragma unroll
  for (int mtl = 0; mtl < 2; ++mtl)
#pragma unroll
    for (int r = 0; r < 16; ++r)
      vmn[mtl][r] = fminf(fminf(acc[mtl][0][r], acc[mtl][1][r]),
                          fminf(acc[mtl][2][r], acc[mtl][3][r]));
#pragma unroll
  for (int off = 1; off <= 16; off <<= 1) {
#pragma unroll
    for (int mtl = 0; mtl < 2; ++mtl)
#pragma unroll
      for (int r = 0; r < 16; ++r)
        vmn[mtl][r] = fminf(vmn[mtl][r], __shfl_xor(vmn[mtl][r], off, 64));
  }
  if (mrow == 0) {   // lanes 0 and 32 publish their half's rows
#pragma unroll
    for (int mtl = 0; mtl < 2; ++mtl)
#pragma unroll
      for (int r = 0; r < 16; ++r) {
        int row = (r & 3) + 8 * (r >> 2) + 4 * khalf;
        scratch[wv * 64 + mtl * 32 + row] = vmn[mtl][r];
      }
  }
  __syncthreads();
  int oh = oh0 + wv;
  if (oh < OHH) {
    float v = scratch[wv * 64 + lane];
    v = tanhf(tanhf(v));
    out[(size_t)n * (OHH * OWW) + (size_t)oh * OWW + ow0 + lane] = v;
  }
}

// ---------------------------------------------------------------------------
// Fallback (only if ws too small): direct fp32 conv, 8 px per block.
// ---------------------------------------------------------------------------
__global__ __launch_bounds__(128) void fallback_kernel(
    const float* __restrict__ x, const float* __restrict__ wt,
    const float* __restrict__ bias, float* __restrict__ out) {
  __shared__ float patch[64 * 30];   // [ci][kh 0..2][wl 0..9]
  __shared__ float red[128];
  int pb   = blockIdx.x;
  int owt  = pb % 28;
  int rest = pb / 28;
  int oh   = rest % OHH;
  int n    = rest / OHH;
  int ow0  = owt * 8;
  int tid  = threadIdx.x;
  for (int i = tid; i < 1920; i += 128) {
    int wl = i % 10;
    int rr = (i / 10) % 3;
    int ci = i / 30;
    int wg = ow0 + wl;
    float v = 0.f;
    if (wg < WW) v = x[((size_t)(n * 64 + ci) * HH + (oh + rr)) * WW + wg];
    patch[i] = v;
  }
  __syncthreads();
  int co = tid;
  float a[8];
#pragma unroll
  for (int p = 0; p < 8; ++p) a[p] = bias[co];
  for (int ci = 0; ci < 64; ++ci) {
#pragma unroll
    for (int rr = 0; rr < 3; ++rr)
#pragma unroll
      for (int kw = 0; kw < 3; ++kw) {
        float wvv = wt[(size_t)co * 576 + ci * 9 + rr * 3 + kw];
        const float* pp = &patch[ci * 30 + rr * 10 + kw];
#pragma unroll
        for (int p = 0; p < 8; ++p) a[p] += pp[p] * wvv;
      }
  }
  for (int p = 0; p < 8; ++p) {
    red[tid] = a[p];
    __syncthreads();
    for (int st = 64; st > 0; st >>= 1) {
      if (tid < st) red[tid] = fminf(red[tid], red[tid + st]);
      __syncthreads();
    }
    if (tid == 0 && (ow0 + p) < OWW)
      out[(size_t)n * (OHH * OWW) + (size_t)oh * OWW + ow0 + p] = tanhf(tanhf(red[0]));
    __syncthreads();
  }
}

// ---------------------------------------------------------------------------
extern "C" void kernel_launch(void* const* d_in, const int* in_sizes, int n_in,
                              void* d_out, int out_size, void* d_ws, size_t ws_size,
                              hipStream_t stream) {
  const float* x    = (const float*)d_in[0];
  const float* wt   = (const float*)d_in[1];
  const float* bias = (const float*)d_in[2];
  float* out        = (float*)d_out;

  if (ws_size >= WS_NEED) {
    unsigned char* ws = (unsigned char*)d_ws;
    prep_x_kernel<<<XTS_SLOTS / 256, 256, 0, stream>>>(x, ws);
    prep_w_kernel<<<36, 256, 0, stream>>>(wt, ws);
    conv_min_kernel<<<NN * 56 * 4, 256, 0, stream>>>(bias, ws, out);
  } else {
    fallback_kernel<<<NN * OHH * 28, 128, 0, stream>>>(x, wt, bias, out);
  }
}

// Round 2
// 474.492 us; speedup vs baseline: 1.0366x; 1.0366x over previous
//
#include <hip/hip_runtime.h>
#include <math.h>

// Problem constants
#define NN   16
#define CI   64
#define HH   224
#define WW   224
#define CO   128
#define OHH  222
#define OWW  222

// Workspace layout:
//  [0, 147456)                : weight fragments, B-operand pre-swizzled per-lane order
//  [147456, 147456+XTS_BYTES) : x transposed to NHWC bf16, per-w chunk-rotated
//  tail pad 64 KiB            : absorbs DMA overfetch of last blocks (~28 KB)
#define WFRAG_BYTES (36*4*64*16)                 // 147456
#define XTS_OFF     ((size_t)WFRAG_BYTES)
#define XTS_SLOTS   (NN*HH*WW)                   // 802816 (n,h,w) slots, 128 B each
#define XTS_BYTES   ((size_t)XTS_SLOTS*128)      // 102,760,448
#define WS_NEED     (XTS_OFF + XTS_BYTES + 65536)

typedef short  short8  __attribute__((ext_vector_type(8)));
typedef float  f32x16  __attribute__((ext_vector_type(16)));

__device__ static inline unsigned short f2bf(float f) {
  unsigned u = __float_as_uint(f);
  u = (u + 0x7fffu + ((u >> 16) & 1u)) >> 16;   // RNE
  return (unsigned short)u;
}

// ---------------------------------------------------------------------------
// prep_x v2: NCHW fp32 -> ws NHWC bf16, 128 B per (n,h,w) slot, chunk c of 8
// ci stored at position (c + w) & 7 (bank rotation for the conv kernel).
// Coalescing fix vs v1: reads stay 256 B/wave coalesced; the scattered 16 B
// slot writes now go to a 16 KB LDS slot-image, then a linear readback gives
// fully-coalesced 1 KB/wave global stores.
// Block = 256 thr handles 128 slots x 64 ci (blocks never straddle n:
// 50176 % 128 == 0).
// ---------------------------------------------------------------------------
__global__ __launch_bounds__(256) void prep_x_kernel(const float* __restrict__ x,
                                                     unsigned char* __restrict__ ws) {
  __shared__ __align__(16) unsigned char lbuf[128 * 128];   // 16 KB slot image
  int tid   = threadIdx.x;
  int h     = tid & 127;           // slot within tile
  int half  = tid >> 7;            // ci half (chunks 0-3 / 4-7)
  int slot0 = blockIdx.x * 128;
  int n     = slot0 / (HH * WW);
  int hw0   = slot0 - n * (HH * WW);
  int hw    = hw0 + h;
  int w     = hw % WW;
  const float* xp = x + (size_t)n * CI * HH * WW + hw;
#pragma unroll
  for (int cc4 = 0; cc4 < 4; ++cc4) {
    int cc = half * 4 + cc4;       // 16B ci-chunk 0..7 (ci = cc*8 .. cc*8+7)
    unsigned pk[4];
#pragma unroll
    for (int j = 0; j < 4; ++j) {
      float a = xp[(size_t)(cc * 8 + 2 * j    ) * (HH * WW)];
      float b = xp[(size_t)(cc * 8 + 2 * j + 1) * (HH * WW)];
      pk[j] = (unsigned)f2bf(a) | ((unsigned)f2bf(b) << 16);
    }
    *(uint4*)(lbuf + h * 128 + (((cc + w) & 7) << 4)) =
        make_uint4(pk[0], pk[1], pk[2], pk[3]);
  }
  __syncthreads();
  uint4*       dst = (uint4*)(ws + XTS_OFF + (size_t)slot0 * 128);
  const uint4* src = (const uint4*)lbuf;
#pragma unroll
  for (int k = 0; k < 4; ++k)
    dst[k * 256 + tid] = src[k * 256 + tid];
}

// ---------------------------------------------------------------------------
// prep_w: weights [Co][Ci][3][3] fp32 -> B fragments in exact mfma lane order.
// Fragment f = s*4 + ct4, s = tap*4 + cic, tap = kh*3+kw.
// B[k][n]: n = lane&31 (co within tile), k = (lane>>5)*8 + j  (ci within cic).
// ---------------------------------------------------------------------------
__global__ __launch_bounds__(256) void prep_w_kernel(const float* __restrict__ wt,
                                                     unsigned char* __restrict__ ws) {
  int t    = blockIdx.x * 256 + threadIdx.x;       // 0..9215
  int lane = t & 63;
  int f    = t >> 6;                               // 0..143
  int s    = f >> 2;
  int ct   = f & 3;
  int tap  = s >> 2;
  int cic  = s & 3;
  int kh   = tap / 3, kw = tap % 3;
  int co   = ct * 32 + (lane & 31);
  int k0   = cic * 16 + (lane >> 5) * 8;
  unsigned int pk[4];
#pragma unroll
  for (int j = 0; j < 4; ++j) {
    int ci0 = k0 + 2 * j;
    float a = wt[(size_t)co * 576 + (ci0    ) * 9 + kh * 3 + kw];
    float b = wt[(size_t)co * 576 + (ci0 + 1) * 9 + kh * 3 + kw];
    pk[j] = (unsigned)f2bf(a) | ((unsigned)f2bf(b) << 16);
  }
  ((uint4*)ws)[t] = make_uint4(pk[0], pk[1], pk[2], pk[3]);
}

// ---------------------------------------------------------------------------
// conv v2: block = 512 thr (8 waves) covering 256 px (4 oh x 64 ow) x 128 co.
// Wave (mg, ng): mg = oh row (2 m-tiles of 32 owl), ng = co half (2 co-tiles).
// B fragments register-resident per kh-chunk (12 steps x 2 ct = 96 VGPRs,
// reloaded 3x per pass) -> B-VMEM off the per-MFMA critical path (R1 limiter).
// A staged once per block via global_load_lds; K-loop barrier-free.
// ---------------------------------------------------------------------------
__device__ static inline void lds_dma16(void* lds, const void* g) {
  __builtin_amdgcn_global_load_lds(
      (__attribute__((address_space(1))) void*)g,
      (__attribute__((address_space(3))) void*)lds, 16, 0, 0);
}

__global__ __launch_bounds__(512, 2) void conv_min_kernel(
    const float* __restrict__ bias, const unsigned char* __restrict__ ws,
    float* __restrict__ out) {
  __shared__ __align__(16) unsigned char smem[6 * 72 * 128];  // 55296 B
  __shared__ float scratch[2][256];

  int bid  = blockIdx.x;
  int owt  = bid & 3;
  int rest = bid >> 2;
  int oht  = rest % 56;
  int n    = rest / 56;
  int ow0  = (owt < 3) ? owt * 64 : 158;   // last tile overlaps; identical values
  int oh0  = oht * 4;                      // oh 222/223 masked at store

  int tid   = threadIdx.x;
  int wv    = tid >> 6;
  int lane  = tid & 63;
  int mg    = wv & 3;     // oh row within tile
  int ng    = wv >> 2;    // co half (64 co)
  int mrow  = lane & 31;
  int khalf = lane >> 5;

  // ---- stage A tile: 6 rows x (72 w x 64 ci bf16) = 6 x 9216 B, DMA ----
  const unsigned char* xts = ws + XTS_OFF;
  size_t gbase = ((size_t)(n * 224 + oh0) * 224 + ow0) * 128;
  for (int i = wv; i < 54; i += 8) {
    int r   = i / 9;
    int sub = i - r * 9;
    lds_dma16(smem + r * 9216 + sub * 1024,
              xts + gbase + (size_t)r * (224 * 128) + sub * 1024 + lane * 16);
  }

  const short8* wf = (const short8*)ws;

  // ---- preload kh=0 B-chunk while DMA is in flight ----
  short8 bf[12][2];   // [kw*4+cic][ct]  -- 96 VGPRs
#pragma unroll
  for (int i = 0; i < 12; ++i)
#pragma unroll
    for (int ct = 0; ct < 2; ++ct)
      bf[i][ct] = wf[(size_t)((i * 4) + ng * 2 + ct) * 64 + lane];

  // ---- acc init with bias (C/D col = co-within-tile = lane&31) ----
  f32x16 acc[2][2];   // [mtl][ct]
#pragma unroll
  for (int ct = 0; ct < 2; ++ct) {
    float b = bias[ng * 64 + ct * 32 + mrow];
#pragma unroll
    for (int mtl = 0; mtl < 2; ++mtl)
#pragma unroll
      for (int r = 0; r < 16; ++r) acc[mtl][ct][r] = b;
  }

  __syncthreads();   // drains DMA (vmcnt) + all waves staged

  // ---- K loop: 3 kh-chunks x (3 kw x 4 cic), barrier-free ----
#pragma unroll 1     // keep bf[] chunked: full unroll would hoist 288 regs of B
  for (int kh = 0; kh < 3; ++kh) {
    if (kh > 0) {
#pragma unroll
      for (int i = 0; i < 12; ++i)
#pragma unroll
        for (int ct = 0; ct < 2; ++ct)
          bf[i][ct] = wf[(size_t)((kh * 12 + i) * 4 + ng * 2 + ct) * 64 + lane];
    }
    int rowb = (mg + kh) * 72;
#pragma unroll
    for (int kw = 0; kw < 3; ++kw) {
#pragma unroll
      for (int cic = 0; cic < 4; ++cic) {
        int c    = cic * 2 + khalf;          // 16B ci-chunk index 0..7
        int col0 = mrow + kw;                // m-tile 0: owl = mrow
        int col1 = mrow + 32 + kw;           // m-tile 1: owl = mrow+32
        short8 a0 = *(const short8*)(smem + (rowb + col0) * 128 + (((c + ow0 + col0) & 7) << 4));
        short8 a1 = *(const short8*)(smem + (rowb + col1) * 128 + (((c + ow0 + col1) & 7) << 4));
#pragma unroll
        for (int ct = 0; ct < 2; ++ct) {
          acc[0][ct] = __builtin_amdgcn_mfma_f32_32x32x16_bf16(a0, bf[kw * 4 + cic][ct], acc[0][ct], 0, 0, 0);
          acc[1][ct] = __builtin_amdgcn_mfma_f32_32x32x16_bf16(a1, bf[kw * 4 + cic][ct], acc[1][ct], 0, 0, 0);
        }
      }
    }
  }

  // ---- epilogue: min over 128 co ----
  // C/D layout (m74/m101): col = lane&31 (co), row = (reg&3)+8*(reg>>2)+4*(lane>>5)
  float vmn[2][16];
#pragma unroll
  for (int mtl = 0; mtl < 2; ++mtl)
#pragma unroll
    for (int r = 0; r < 16; ++r)
      vmn[mtl][r] = fminf(acc[mtl][0][r], acc[mtl][1][r]);
#pragma unroll
  for (int off = 1; off <= 16; off <<= 1) {
#pragma unroll
    for (int mtl = 0; mtl < 2; ++mtl)
#pragma unroll
      for (int r = 0; r < 16; ++r)
        vmn[mtl][r] = fminf(vmn[mtl][r], __shfl_xor(vmn[mtl][r], off, 64));
  }
  if (mrow == 0) {   // lanes 0 and 32 publish their half's rows
#pragma unroll
    for (int mtl = 0; mtl < 2; ++mtl)
#pragma unroll
      for (int r = 0; r < 16; ++r) {
        int row = (r & 3) + 8 * (r >> 2) + 4 * khalf;
        scratch[ng][mg * 64 + mtl * 32 + row] = vmn[mtl][r];
      }
  }
  __syncthreads();
  if (tid < 256) {
    int oh = oh0 + (tid >> 6);
    if (oh < OHH) {
      float v = fminf(scratch[0][tid], scratch[1][tid]);
      v = tanhf(tanhf(v));
      out[(size_t)n * (OHH * OWW) + (size_t)oh * OWW + ow0 + (tid & 63)] = v;
    }
  }
}

// ---------------------------------------------------------------------------
// Fallback (only if ws too small): direct fp32 conv, 8 px per block.
// ---------------------------------------------------------------------------
__global__ __launch_bounds__(128) void fallback_kernel(
    const float* __restrict__ x, const float* __restrict__ wt,
    const float* __restrict__ bias, float* __restrict__ out) {
  __shared__ float patch[64 * 30];
  __shared__ float red[128];
  int pb   = blockIdx.x;
  int owt  = pb % 28;
  int rest = pb / 28;
  int oh   = rest % OHH;
  int n    = rest / OHH;
  int ow0  = owt * 8;
  int tid  = threadIdx.x;
  for (int i = tid; i < 1920; i += 128) {
    int wl = i % 10;
    int rr = (i / 10) % 3;
    int ci = i / 30;
    int wg = ow0 + wl;
    float v = 0.f;
    if (wg < WW) v = x[((size_t)(n * 64 + ci) * HH + (oh + rr)) * WW + wg];
    patch[i] = v;
  }
  __syncthreads();
  int co = tid;
  float a[8];
#pragma unroll
  for (int p = 0; p < 8; ++p) a[p] = bias[co];
  for (int ci = 0; ci < 64; ++ci) {
#pragma unroll
    for (int rr = 0; rr < 3; ++rr)
#pragma unroll
      for (int kw = 0; kw < 3; ++kw) {
        float wvv = wt[(size_t)co * 576 + ci * 9 + rr * 3 + kw];
        const float* pp = &patch[ci * 30 + rr * 10 + kw];
#pragma unroll
        for (int p = 0; p < 8; ++p) a[p] += pp[p] * wvv;
      }
  }
  for (int p = 0; p < 8; ++p) {
    red[tid] = a[p];
    __syncthreads();
    for (int st = 64; st > 0; st >>= 1) {
      if (tid < st) red[tid] = fminf(red[tid], red[tid + st]);
      __syncthreads();
    }
    if (tid == 0 && (ow0 + p) < OWW)
      out[(size_t)n * (OHH * OWW) + (size_t)oh * OWW + ow0 + p] = tanhf(tanhf(red[0]));
    __syncthreads();
  }
}

// ---------------------------------------------------------------------------
extern "C" void kernel_launch(void* const* d_in, const int* in_sizes, int n_in,
                              void* d_out, int out_size, void* d_ws, size_t ws_size,
                              hipStream_t stream) {
  const float* x    = (const float*)d_in[0];
  const float* wt   = (const float*)d_in[1];
  const float* bias = (const float*)d_in[2];
  float* out        = (float*)d_out;

  if (ws_size >= WS_NEED) {
    unsigned char* ws = (unsigned char*)d_ws;
    prep_x_kernel<<<XTS_SLOTS / 128, 256, 0, stream>>>(x, ws);
    prep_w_kernel<<<36, 256, 0, stream>>>(wt, ws);
    conv_min_kernel<<<NN * 56 * 4, 512, 0, stream>>>(bias, ws, out);
  } else {
    fallback_kernel<<<NN * OHH * 28, 128, 0, stream>>>(x, wt, bias, out);
  }
}

// Round 3
// 419.084 us; speedup vs baseline: 1.1737x; 1.1322x over previous
//
#include <hip/hip_runtime.h>
#include <hip/hip_bf16.h>
#include <math.h>

// Problem constants
#define NN   16
#define CI   64
#define HH   224
#define WW   224
#define CO   128
#define OHH  222
#define OWW  222

// ws now holds ONLY prep_w's B fragments (144 KB) -> tiny poison cost.
#define WS_NEED (36*4*64*16)   // 147456

typedef short  short8  __attribute__((ext_vector_type(8)));
typedef float  f32x16  __attribute__((ext_vector_type(16)));
typedef float  f32x4   __attribute__((ext_vector_type(4)));

__device__ static inline unsigned f2bf_pk(float a, float b) {
  __hip_bfloat162 h = __float22bfloat162_rn(make_float2(a, b));  // v_cvt_pk_bf16_f32
  return *reinterpret_cast<unsigned*>(&h);
}

// ---------------------------------------------------------------------------
// prep_w: weights [Co][Ci][3][3] fp32 -> B fragments in mfma lane order.
// frag (s, ctg): s = tap*4+cic (tap=kh*3+kw), ctg 0..3; element ((s*4+ctg)*64+lane).
// B[k][n]: n = lane&31 (co within 32-tile), k = (lane>>5)*8 + j.
// ---------------------------------------------------------------------------
__global__ __launch_bounds__(256) void prep_w_kernel(const float* __restrict__ wt,
                                                     unsigned char* __restrict__ ws) {
  int t    = blockIdx.x * 256 + threadIdx.x;       // 0..9215
  int lane = t & 63;
  int f    = t >> 6;                               // 0..143
  int s    = f >> 2;
  int ct   = f & 3;
  int tap  = s >> 2;
  int cic  = s & 3;
  int kh   = tap / 3, kw = tap % 3;
  int co   = ct * 32 + (lane & 31);
  int k0   = cic * 16 + (lane >> 5) * 8;
  unsigned pk[4];
#pragma unroll
  for (int j = 0; j < 4; ++j) {
    int ci0 = k0 + 2 * j;
    float a = wt[(size_t)co * 576 + (ci0    ) * 9 + kh * 3 + kw];
    float b = wt[(size_t)co * 576 + (ci0 + 1) * 9 + kh * 3 + kw];
    pk[j] = f2bf_pk(a, b);
  }
  ((uint4*)ws)[t] = make_uint4(pk[0], pk[1], pk[2], pk[3]);
}

// ---------------------------------------------------------------------------
// conv v3: fused staging + implicit GEMM + min + tanh^2.
// Block 256 thr / 4 waves covers 4 oh x 64 ow x 128 co.
// Wave (mg = wv>>1, ng = wv&1): 4 m-tiles (ohl,owh) x 2 co-tiles; acc 128 VGPR.
// A staged in-kernel from NCHW fp32 (bank-rotated bf16 slots); B from ws via
// register triple-buffer; ds_read addresses are P[j] + compile-time offset.
// ---------------------------------------------------------------------------
__global__ __launch_bounds__(256, 2) void conv_min_kernel(
    const float* __restrict__ x, const float* __restrict__ bias,
    const unsigned char* __restrict__ ws, float* __restrict__ out) {
  __shared__ __align__(16) unsigned char smem[6 * 72 * 128];  // 55296 B

  int bid  = blockIdx.x;
  int owt  = bid & 3;
  int rest = bid >> 2;
  int oht  = rest % 56;
  int n    = rest / 56;
  int ow0  = (owt < 3) ? owt * 64 : 158;   // last ow tile overlaps (same values)
  int oh0  = oht * 4;                      // oh 222/223 masked at store

  int tid   = threadIdx.x;
  int wv    = tid >> 6;
  int lane  = tid & 63;
  int mg    = wv >> 1;     // oh row-pair
  int ng    = wv & 1;      // co half
  int mrow  = lane & 31;
  int khalf = lane >> 5;

  // ---- B prologue (issue before staging so loads overlap) ----
  const short8* wf = (const short8*)ws;
  int bbase = ng * 128 + lane;
  short8 bb[3][2];
#pragma unroll
  for (int ct = 0; ct < 2; ++ct) bb[0][ct] = wf[0 * 256 + ct * 64 + bbase];
#pragma unroll
  for (int ct = 0; ct < 2; ++ct) bb[1][ct] = wf[1 * 256 + ct * 64 + bbase];

  // ---- in-kernel A staging: 6 rows x 72 cols x 64 ci bf16, rotated slots ----
  // slot(row,col): chunk cc (ci 8cc..8cc+7) at byte ((cc+col)&7)*16, word pp&3.
  {
    int colm = (tid & 31) * 2;     // main cols 0..63 (pairs)
    int q    = (tid >> 5) & 7;     // ci-pair group
    int cole = 64 + (tid & 7);     // extra cols 64..71
    int ppe  = tid >> 3;           // ci-pair 0..31 for extra path
    const float* xb = x + (size_t)n * 64 * 50176;
#pragma unroll 1
    for (int r = 0; r < 6; ++r) {
      int rg = oh0 + r; if (rg > 223) rg = 223;
      const float* xr = xb + (size_t)rg * 224;
#pragma unroll
      for (int p = 0; p < 4; ++p) {
        int pp = p * 8 + q;
        int ci = pp * 2;
        const float* s0 = xr + (size_t)ci * 50176 + ow0 + colm;
        float2 a2 = *(const float2*)s0;
        float2 b2 = *(const float2*)(s0 + 50176);
        unsigned u0 = f2bf_pk(a2.x, b2.x);
        unsigned u1 = f2bf_pk(a2.y, b2.y);
        int cc = pp >> 2, jw = (pp & 3) * 4;
        *(unsigned*)(smem + (r * 72 + colm    ) * 128 + (((cc + colm    ) & 7) << 4) + jw) = u0;
        *(unsigned*)(smem + (r * 72 + colm + 1) * 128 + (((cc + colm + 1) & 7) << 4) + jw) = u1;
      }
      {   // extra cols (clamped; cols 66..71 never read by MFMA)
        int colg = ow0 + cole; if (colg > 223) colg = 223;
        const float* s0 = xr + (size_t)(ppe * 2) * 50176 + colg;
        float a = s0[0], b = s0[50176];
        *(unsigned*)(smem + (r * 72 + cole) * 128 + ((((ppe >> 2) + cole) & 7) << 4) + (ppe & 3) * 4) =
            f2bf_pk(a, b);
      }
    }
  }

  // ---- acc init with bias ----
  f32x16 acc[4][2];
#pragma unroll
  for (int ct = 0; ct < 2; ++ct) {
    float bv = bias[ng * 64 + ct * 32 + mrow];
#pragma unroll
    for (int mtl = 0; mtl < 4; ++mtl)
#pragma unroll
      for (int r = 0; r < 16; ++r) acc[mtl][ct][r] = bv;
  }

  // ---- zero-VALU LDS read pointers ----
  unsigned uu = (mrow + khalf) & 7;
  const unsigned char* Pb = smem + mg * 18432 + mrow * 128;
  const unsigned char* P[8];
#pragma unroll
  for (int j = 0; j < 8; ++j) P[j] = Pb + ((uu + j) & 7) * 16;

  __syncthreads();

  // ---- A preload step 0 ----
  short8 aa[2][4];
#pragma unroll
  for (int mtl = 0; mtl < 4; ++mtl) {
    const int ohl = mtl >> 1, owh = mtl & 1;
    aa[0][mtl] = *(const short8*)(P[0] + ((ohl * 72 + owh * 32) << 7));
  }

  // ---- K loop: 36 steps (tap,cic), fully unrolled, barrier-free ----
#pragma unroll
  for (int s = 0; s < 36; ++s) {
    if (s + 2 < 36) {
#pragma unroll
      for (int ct = 0; ct < 2; ++ct)
        bb[(s + 2) % 3][ct] = wf[(s + 2) * 256 + ct * 64 + bbase];
    }
    if (s + 1 < 36) {
      const int s1 = s + 1;
      const int kh1 = s1 / 12, kw1 = (s1 / 4) % 3, cic1 = s1 & 3;
      const int j1 = (2 * cic1 + kw1) & 7;
#pragma unroll
      for (int mtl = 0; mtl < 4; ++mtl) {
        const int ohl = mtl >> 1, owh = mtl & 1;
        aa[s1 & 1][mtl] =
            *(const short8*)(P[j1] + ((((ohl + kh1) * 72) + kw1 + owh * 32) << 7));
      }
    }
#pragma unroll
    for (int mtl = 0; mtl < 4; ++mtl)
#pragma unroll
      for (int ct = 0; ct < 2; ++ct)
        acc[mtl][ct] = __builtin_amdgcn_mfma_f32_32x32x16_bf16(
            aa[s & 1][mtl], bb[s % 3][ct], acc[mtl][ct], 0, 0, 0);
  }

  // ---- epilogue ----
  // C/D: col = lane&31 (co), row = (r&3)+8*(r>>2)+4*khalf (pixel m).
  __syncthreads();          // A-tile dead; reuse smem for reduction
  float* epi = (float*)smem;  // [px 256][36 words]: ng*16 + co' in words 0..31
#pragma unroll
  for (int mtl = 0; mtl < 4; ++mtl) {
    const int ohl = mtl >> 1, owh = mtl & 1;
#pragma unroll
    for (int r = 0; r < 16; ++r) {
      float v = fminf(acc[mtl][0][r], acc[mtl][1][r]);       // min over ct
      v = fminf(v, __shfl_xor(v, 16, 64));                   // min over co pairs
      if ((lane & 16) == 0) {
        int px = (mg * 2 + ohl) * 64 + owh * 32 + ((r & 3) + 8 * (r >> 2) + 4 * khalf);
        epi[px * 36 + ng * 16 + (lane & 15)] = v;
      }
    }
  }
  __syncthreads();
  {
    int px = tid;
    int rowsel = px >> 6;
    int oh = oh0 + rowsel;
    const f32x4* rowp = (const f32x4*)(epi + px * 36);
    f32x4 m4 = rowp[0];
#pragma unroll
    for (int k = 1; k < 8; ++k) {
      f32x4 t = rowp[k];
      m4[0] = fminf(m4[0], t[0]); m4[1] = fminf(m4[1], t[1]);
      m4[2] = fminf(m4[2], t[2]); m4[3] = fminf(m4[3], t[3]);
    }
    float v = fminf(fminf(m4[0], m4[1]), fminf(m4[2], m4[3]));
    v = tanhf(tanhf(v));
    if (oh < OHH)
      out[(size_t)n * (OHH * OWW) + (size_t)oh * OWW + ow0 + (px & 63)] = v;
  }
}

// ---------------------------------------------------------------------------
// Fallback (only if ws too small): direct fp32 conv, 8 px per block.
// ---------------------------------------------------------------------------
__global__ __launch_bounds__(128) void fallback_kernel(
    const float* __restrict__ x, const float* __restrict__ wt,
    const float* __restrict__ bias, float* __restrict__ out) {
  __shared__ float patch[64 * 30];
  __shared__ float red[128];
  int pb   = blockIdx.x;
  int owt  = pb % 28;
  int rest = pb / 28;
  int oh   = rest % OHH;
  int n    = rest / OHH;
  int ow0  = owt * 8;
  int tid  = threadIdx.x;
  for (int i = tid; i < 1920; i += 128) {
    int wl = i % 10;
    int rr = (i / 10) % 3;
    int ci = i / 30;
    int wg = ow0 + wl;
    float v = 0.f;
    if (wg < WW) v = x[((size_t)(n * 64 + ci) * HH + (oh + rr)) * WW + wg];
    patch[i] = v;
  }
  __syncthreads();
  int co = tid;
  float a[8];
#pragma unroll
  for (int p = 0; p < 8; ++p) a[p] = bias[co];
  for (int ci = 0; ci < 64; ++ci) {
#pragma unroll
    for (int rr = 0; rr < 3; ++rr)
#pragma unroll
      for (int kw = 0; kw < 3; ++kw) {
        float wvv = wt[(size_t)co * 576 + ci * 9 + rr * 3 + kw];
        const float* pp = &patch[ci * 30 + rr * 10 + kw];
#pragma unroll
        for (int p = 0; p < 8; ++p) a[p] += pp[p] * wvv;
      }
  }
  for (int p = 0; p < 8; ++p) {
    red[tid] = a[p];
    __syncthreads();
    for (int st = 64; st > 0; st >>= 1) {
      if (tid < st) red[tid] = fminf(red[tid], red[tid + st]);
      __syncthreads();
    }
    if (tid == 0 && (ow0 + p) < OWW)
      out[(size_t)n * (OHH * OWW) + (size_t)oh * OWW + ow0 + p] = tanhf(tanhf(red[0]));
    __syncthreads();
  }
}

// ---------------------------------------------------------------------------
extern "C" void kernel_launch(void* const* d_in, const int* in_sizes, int n_in,
                              void* d_out, int out_size, void* d_ws, size_t ws_size,
                              hipStream_t stream) {
  const float* x    = (const float*)d_in[0];
  const float* wt   = (const float*)d_in[1];
  const float* bias = (const float*)d_in[2];
  float* out        = (float*)d_out;

  if (ws_size >= WS_NEED) {
    unsigned char* ws = (unsigned char*)d_ws;
    prep_w_kernel<<<36, 256, 0, stream>>>(wt, ws);
    conv_min_kernel<<<NN * 56 * 4, 256, 0, stream>>>(x, bias, ws, out);
  } else {
    fallback_kernel<<<NN * OHH * 28, 128, 0, stream>>>(x, wt, bias, out);
  }
}